// Round 1
// baseline (367.627 us; speedup 1.0000x reference)
//
#include <hip/hip_runtime.h>

// ISTFT: B=64, FRAMES=512, BINS=513, FFT_LEN=1024, STRIDE=256
// out: (64, 130816) fp32
#define BATCH    64
#define FRAMES   512
#define BINS     513
#define OUT_LEN  130816            // 256*511
#define TWO_PI   6.2831853071795864769f

__device__ __forceinline__ float2 cadd(float2 a, float2 b){ return make_float2(a.x+b.x, a.y+b.y); }
__device__ __forceinline__ float2 csub(float2 a, float2 b){ return make_float2(a.x-b.x, a.y-b.y); }
__device__ __forceinline__ float2 cmul(float2 a, float2 b){
    return make_float2(a.x*b.x - a.y*b.y, a.x*b.y + a.y*b.x);
}
// LDS bank-conflict padding: one extra complex every 8
__device__ __forceinline__ int phys(int i){ return i + (i >> 3); }

// 8-point inverse DFT (positive twiddle sign), in place.
__device__ __forceinline__ void bfly8(float2 v[8]) {
    float2 t0 = cadd(v[0], v[4]), t1 = csub(v[0], v[4]);
    float2 t2 = cadd(v[2], v[6]), t3 = csub(v[2], v[6]);
    float2 E0 = cadd(t0, t2), E2 = csub(t0, t2);
    float2 E1 = make_float2(t1.x - t3.y, t1.y + t3.x);   // t1 + i*t3
    float2 E3 = make_float2(t1.x + t3.y, t1.y - t3.x);   // t1 - i*t3
    float2 u0 = cadd(v[1], v[5]), u1 = csub(v[1], v[5]);
    float2 u2 = cadd(v[3], v[7]), u3 = csub(v[3], v[7]);
    float2 O0 = cadd(u0, u2), O2 = csub(u0, u2);
    float2 O1 = make_float2(u1.x - u3.y, u1.y + u3.x);
    float2 O3 = make_float2(u1.x + u3.y, u1.y - u3.x);
    const float C = 0.70710678118654752440f;
    float2 w1 = make_float2(C*(O1.x - O1.y),  C*(O1.x + O1.y));   // W8^1 * O1
    float2 w2 = make_float2(-O2.y, O2.x);                         // i * O2
    float2 w3 = make_float2(-C*(O3.x + O3.y), C*(O3.x - O3.y));   // W8^3 * O3
    v[0] = cadd(E0, O0); v[4] = csub(E0, O0);
    v[1] = cadd(E1, w1); v[5] = csub(E1, w1);
    v[2] = cadd(E2, w2); v[6] = csub(E2, w2);
    v[3] = cadd(E3, w3); v[7] = csub(E3, w3);
}

// One wave (64 lanes) per frame; block = 4 waves = 4 frames.
__global__ __launch_bounds__(256) void istft_kernel(
    const float* __restrict__ re_g, const float* __restrict__ im_g,
    float* __restrict__ out)
{
    // per-wave ping-pong buffers (padded: logical 513 -> phys 577; 512 -> 575)
    __shared__ float2 Abuf[4][584];
    __shared__ float2 Bbuf[4][576];

    const int tid  = threadIdx.x;
    const int wave = tid >> 6;
    const int lane = tid & 63;
    const int frame = blockIdx.x * 4 + wave;
    const int b = frame >> 9;          // FRAMES = 512
    const int f = frame & 511;

    float2* A  = Abuf[wave];
    float2* Bb = Bbuf[wave];

    const long long off = (long long)frame * BINS;
    const float* re = re_g + off;
    const float* im = im_g + off;

    // ---- load X[0..512]; irfft ignores Im of DC & Nyquist ----
    #pragma unroll
    for (int j = 0; j < 9; ++j) {
        int k = lane + 64*j;
        if (k < BINS) {
            float r = re[k];
            float i2 = im[k];
            if (k == 0 || k == 512) i2 = 0.0f;
            A[phys(k)] = make_float2(r, i2);
        }
    }
    __syncthreads();

    // ---- pack into 512-pt complex spectrum Z (scaled by 1/1024) ----
    // Z[k] = (S + i*t*D) / 1024,  S = X[k]+conj(X[512-k]), D = X[k]-conj(X[512-k]),
    // t = e^{+2pi i k/1024}
    #pragma unroll
    for (int j = 0; j < 8; ++j) {
        int k = lane + 64*j;
        float2 Xa = A[phys(k)];
        float2 Xc = A[phys(512 - k)];
        float Sx = Xa.x + Xc.x, Sy = Xa.y - Xc.y;
        float Dx = Xa.x - Xc.x, Dy = Xa.y + Xc.y;
        float s, c;
        sincosf((float)k * (TWO_PI / 1024.0f), &s, &c);
        float zx = (Sx - c*Dy - s*Dx) * (1.0f/1024.0f);
        float zy = (Sy + c*Dx - s*Dy) * (1.0f/1024.0f);
        Bb[phys(k)] = make_float2(zx, zy);
    }
    __syncthreads();

    // ---- 512-pt inverse FFT: 3 x radix-8 Stockham (autosorted) ----
    // stage 1: n=512, s=1: read Bb[l+64r] -> write A[8l+t] * e^{2pi i l t/512}
    {
        float2 v[8];
        #pragma unroll
        for (int r = 0; r < 8; ++r) v[r] = Bb[phys(lane + 64*r)];
        bfly8(v);
        float s, c; sincosf((float)lane * (TWO_PI / 512.0f), &s, &c);
        float2 w = make_float2(c, s);
        float2 tw = make_float2(1.0f, 0.0f);
        int base = phys(8*lane);   // == 9*lane, t=0..7 contiguous
        #pragma unroll
        for (int t = 0; t < 8; ++t) {
            A[base + t] = cmul(v[t], tw);
            tw = cmul(tw, w);
        }
    }
    __syncthreads();

    // stage 2: n=64, s=8: p=l>>3, q=l&7: read A[l+64r] -> write Bb[q+64p+8t] * e^{2pi i p t/64}
    {
        float2 v[8];
        #pragma unroll
        for (int r = 0; r < 8; ++r) v[r] = A[phys(lane + 64*r)];
        bfly8(v);
        int p = lane >> 3, q = lane & 7;
        float s, c; sincosf((float)p * (TWO_PI / 64.0f), &s, &c);
        float2 w = make_float2(c, s);
        float2 tw = make_float2(1.0f, 0.0f);
        #pragma unroll
        for (int t = 0; t < 8; ++t) {
            Bb[phys(q + 64*p + 8*t)] = cmul(v[t], tw);
            tw = cmul(tw, w);
        }
    }
    __syncthreads();

    // stage 3: n=8, s=64: read Bb[l+64r] -> write A[l+64t], no twiddle
    {
        float2 v[8];
        #pragma unroll
        for (int r = 0; r < 8; ++r) v[r] = Bb[phys(lane + 64*r)];
        bfly8(v);
        #pragma unroll
        for (int t = 0; t < 8; ++t) A[phys(lane + 64*t)] = v[t];
    }
    __syncthreads();

    // ---- window + overlap-add (A[n] = x[2n] + i x[2n+1]) ----
    // win[m] = (0.5 - 0.5 cos(2 pi m/1024)) / 1.5 ; out[t] += frame, t = 256 f + m - 512
    const float WS = 2.0f / 3.0f;
    float* outb = out + (long long)b * OUT_LEN;
    const int ubase = 256*f - 512;
    #pragma unroll
    for (int j = 0; j < 8; ++j) {
        int n = lane + 64*j;
        float2 z = A[phys(n)];
        int m = 2*n;
        float w0 = (0.5f - 0.5f*cosf((float)m       * (TWO_PI / 1024.0f))) * WS;
        float w1 = (0.5f - 0.5f*cosf((float)(m + 1) * (TWO_PI / 1024.0f))) * WS;
        int t0 = ubase + m;
        if (t0 >= 0 && t0 < OUT_LEN) atomicAdd(&outb[t0], z.x * w0);
        int t1 = t0 + 1;
        if (t1 >= 0 && t1 < OUT_LEN) atomicAdd(&outb[t1], z.y * w1);
    }
}

extern "C" void kernel_launch(void* const* d_in, const int* in_sizes, int n_in,
                              void* d_out, int out_size, void* d_ws, size_t ws_size,
                              hipStream_t stream) {
    const float* real = (const float*)d_in[0];
    const float* imag = (const float*)d_in[1];
    float* out = (float*)d_out;

    // zero output (atomic accumulation target); stream-ordered -> capture-safe
    hipMemsetAsync(out, 0, (size_t)out_size * sizeof(float), stream);

    const int total_frames = BATCH * FRAMES;      // 32768
    dim3 grid(total_frames / 4);                  // 4 frames (waves) per block
    dim3 block(256);
    istft_kernel<<<grid, block, 0, stream>>>(real, imag, out);
}

// Round 2
// 204.576 us; speedup vs baseline: 1.7970x; 1.7970x over previous
//
#include <hip/hip_runtime.h>

// ISTFT: B=64, FRAMES=512, BINS=513, FFT_LEN=1024, STRIDE=256
// out: (64, 130816) fp32
#define BATCH    64
#define FRAMES   512
#define BINS     513
#define OUT_LEN  130816            // 256*511
#define TWO_PI   6.2831853071795864769f
#define HOPS_PER_BLOCK 13          // owned output hops; frames needed = 13+3 = 16 waves

__device__ __forceinline__ float2 cadd(float2 a, float2 b){ return make_float2(a.x+b.x, a.y+b.y); }
__device__ __forceinline__ float2 csub(float2 a, float2 b){ return make_float2(a.x-b.x, a.y-b.y); }
__device__ __forceinline__ float2 cmul(float2 a, float2 b){
    return make_float2(a.x*b.x - a.y*b.y, a.x*b.y + a.y*b.x);
}
// LDS bank-conflict padding: one extra complex every 8
__device__ __forceinline__ int phys(int i){ return i + (i >> 3); }

// 8-point inverse DFT (positive twiddle sign), in place.
__device__ __forceinline__ void bfly8(float2 v[8]) {
    float2 t0 = cadd(v[0], v[4]), t1 = csub(v[0], v[4]);
    float2 t2 = cadd(v[2], v[6]), t3 = csub(v[2], v[6]);
    float2 E0 = cadd(t0, t2), E2 = csub(t0, t2);
    float2 E1 = make_float2(t1.x - t3.y, t1.y + t3.x);   // t1 + i*t3
    float2 E3 = make_float2(t1.x + t3.y, t1.y - t3.x);   // t1 - i*t3
    float2 u0 = cadd(v[1], v[5]), u1 = csub(v[1], v[5]);
    float2 u2 = cadd(v[3], v[7]), u3 = csub(v[3], v[7]);
    float2 O0 = cadd(u0, u2), O2 = csub(u0, u2);
    float2 O1 = make_float2(u1.x - u3.y, u1.y + u3.x);
    float2 O3 = make_float2(u1.x + u3.y, u1.y - u3.x);
    const float C = 0.70710678118654752440f;
    float2 w1 = make_float2(C*(O1.x - O1.y),  C*(O1.x + O1.y));   // W8^1 * O1
    float2 w2 = make_float2(-O2.y, O2.x);                         // i * O2
    float2 w3 = make_float2(-C*(O3.x + O3.y), C*(O3.x - O3.y));   // W8^3 * O3
    v[0] = cadd(E0, O0); v[4] = csub(E0, O0);
    v[1] = cadd(E1, w1); v[5] = csub(E1, w1);
    v[2] = cadd(E2, w2); v[6] = csub(E2, w2);
    v[3] = cadd(E3, w3); v[7] = csub(E3, w3);
}

// Block = 16 waves. Wave w computes frame f = u0-1+w into its LDS buffer;
// gather phase sums the 4 contributing frames per owned output sample.
__global__ __launch_bounds__(1024) void istft_kernel(
    const float* __restrict__ re_g, const float* __restrict__ im_g,
    float* __restrict__ out)
{
    __shared__ float2 Abuf[16][584];   // padded: phys(512)=576 max
    __shared__ float2 Bbuf[16][576];   // phys(511)=574 max
    __shared__ float2 tw[1024];        // (cos,sin)(2*pi*k/1024)

    const int tid  = threadIdx.x;
    const int wave = tid >> 6;
    const int lane = tid & 63;
    const int b    = blockIdx.y;
    const int u0   = blockIdx.x * HOPS_PER_BLOCK;
    const int f    = u0 - 1 + wave;                 // frame this wave computes
    const bool valid = (f >= 0) && (f < FRAMES);

    // ---- shared twiddle/window table: one sincosf per thread per block ----
    {
        float s, c;
        sincosf((float)tid * (TWO_PI / 1024.0f), &s, &c);
        tw[tid] = make_float2(c, s);
    }

    float2* A  = Abuf[wave];
    float2* Bb = Bbuf[wave];

    // ---- load X[0..512]; irfft ignores Im of DC & Nyquist ----
    if (valid) {
        const long long off = (long long)(b * FRAMES + f) * BINS;
        const float* re = re_g + off;
        const float* im = im_g + off;
        #pragma unroll
        for (int j = 0; j < 9; ++j) {
            int k = lane + 64*j;
            if (k < BINS) {
                float r  = re[k];
                float i2 = im[k];
                if (k == 0 || k == 512) i2 = 0.0f;
                A[phys(k)] = make_float2(r, i2);
            }
        }
    }
    __syncthreads();

    // ---- pack into 512-pt complex spectrum Z (scaled by 1/1024) ----
    // Z[k] = (S + i*t*D)/1024, S = X[k]+conj(X[512-k]), D = X[k]-conj(X[512-k]),
    // t = e^{+2pi i k/1024} = tw[k]
    if (valid) {
        #pragma unroll
        for (int j = 0; j < 8; ++j) {
            int k = lane + 64*j;
            float2 Xa = A[phys(k)];
            float2 Xc = A[phys(512 - k)];
            float Sx = Xa.x + Xc.x, Sy = Xa.y - Xc.y;
            float Dx = Xa.x - Xc.x, Dy = Xa.y + Xc.y;
            float2 t2 = tw[k];
            float zx = (Sx - t2.x*Dy - t2.y*Dx) * (1.0f/1024.0f);
            float zy = (Sy + t2.x*Dx - t2.y*Dy) * (1.0f/1024.0f);
            Bb[phys(k)] = make_float2(zx, zy);
        }
    }
    __syncthreads();

    // ---- 512-pt inverse FFT: 3 x radix-8 Stockham (autosorted) ----
    // stage 1: read Bb[l+64r] -> write A[8l+t] * e^{2pi i l t/512}
    if (valid) {
        float2 v[8];
        #pragma unroll
        for (int r = 0; r < 8; ++r) v[r] = Bb[phys(lane + 64*r)];
        bfly8(v);
        float2 w1 = tw[2*lane];                    // e^{2pi i l/512}
        float2 twd = make_float2(1.0f, 0.0f);
        int base = phys(8*lane);                   // == 9*lane; t contiguous
        #pragma unroll
        for (int t = 0; t < 8; ++t) {
            A[base + t] = cmul(v[t], twd);
            twd = cmul(twd, w1);
        }
    }
    __syncthreads();

    // stage 2: p=l>>3, q=l&7: read A[l+64r] -> write Bb[q+64p+8t] * e^{2pi i p t/64}
    if (valid) {
        float2 v[8];
        #pragma unroll
        for (int r = 0; r < 8; ++r) v[r] = A[phys(lane + 64*r)];
        bfly8(v);
        int p = lane >> 3, q = lane & 7;
        float2 w1 = tw[16*p];                      // e^{2pi i p/64}
        float2 twd = make_float2(1.0f, 0.0f);
        #pragma unroll
        for (int t = 0; t < 8; ++t) {
            Bb[phys(q + 64*p + 8*t)] = cmul(v[t], twd);
            twd = cmul(twd, w1);
        }
    }
    __syncthreads();

    // stage 3: read Bb[l+64r] -> write A[l+64t], no twiddle
    if (valid) {
        float2 v[8];
        #pragma unroll
        for (int r = 0; r < 8; ++r) v[r] = Bb[phys(lane + 64*r)];
        bfly8(v);
        #pragma unroll
        for (int t = 0; t < 8; ++t) A[phys(lane + 64*t)] = v[t];
    }
    __syncthreads();

    // ---- gather: out[t] = sum_{q=0..3} win[r+256q] * x_{u+2-q}[r+256q] ----
    // t = 256*u + r; contributing frames f' = u-1..u+2, m = r + 256*(u+2-f').
    // x stored interleaved: x[m] = A[f'-u0+1][phys(m>>1)].{x if m even else y}
    // win[m] = (0.5 - 0.5*cos(2pi m/1024)) / 1.5
    const int nU   = min(HOPS_PER_BLOCK, (OUT_LEN/256) - u0);   // 511 hops total
    const int nOut = nU * 256;
    float* outp = out + (long long)b * OUT_LEN + 256 * u0;
    const float WS = 2.0f / 3.0f;
    for (int tl = tid; tl < nOut; tl += 1024) {
        int r  = tl & 255;
        int u  = u0 + (tl >> 8);
        float sum = 0.0f;
        #pragma unroll
        for (int qq = 0; qq < 4; ++qq) {
            int ff = u + 2 - qq;
            if (ff >= 0 && ff < FRAMES) {
                int w  = ff - u0 + 1;              // wave buffer index, 0..15
                int m  = r + 256*qq;
                float2 z = Abuf[w][phys(m >> 1)];
                float val = (m & 1) ? z.y : z.x;
                float wn = (0.5f - 0.5f * tw[m].x) * WS;
                sum += val * wn;
            }
        }
        outp[tl] = sum;
    }
}

extern "C" void kernel_launch(void* const* d_in, const int* in_sizes, int n_in,
                              void* d_out, int out_size, void* d_ws, size_t ws_size,
                              hipStream_t stream) {
    const float* real = (const float*)d_in[0];
    const float* imag = (const float*)d_in[1];
    float* out = (float*)d_out;

    // 511 output hops per row, 13 per block -> 40 blocks per row; no memset needed
    dim3 grid((OUT_LEN/256 + HOPS_PER_BLOCK - 1) / HOPS_PER_BLOCK, BATCH);
    dim3 block(1024);
    istft_kernel<<<grid, block, 0, stream>>>(real, imag, out);
}

// Round 3
// 168.683 us; speedup vs baseline: 2.1794x; 1.2128x over previous
//
#include <hip/hip_runtime.h>

// ISTFT: B=64, FRAMES=512, BINS=513, FFT_LEN=1024, STRIDE=256
// out: (64, 130816) fp32
#define BATCH    64
#define FRAMES   512
#define BINS     513
#define OUT_LEN  130816            // 256*511
#define TWO_PI   6.2831853071795864769f
#define HOPS_PER_BLOCK 13          // owned output hops; frames needed = 13+3 = 16 waves

__device__ __forceinline__ float2 cadd(float2 a, float2 b){ return make_float2(a.x+b.x, a.y+b.y); }
__device__ __forceinline__ float2 csub(float2 a, float2 b){ return make_float2(a.x-b.x, a.y-b.y); }
__device__ __forceinline__ float2 cmul(float2 a, float2 b){
    return make_float2(a.x*b.x - a.y*b.y, a.x*b.y + a.y*b.x);
}
// LDS bank padding: +1 float2 every 8 -> all stage patterns ~4 lanes/bank-pair (b64 minimum)
__device__ __forceinline__ int phys(int i){ return i + (i >> 3); }

// 8-point inverse DFT (positive twiddle sign), in place.
__device__ __forceinline__ void bfly8(float2 v[8]) {
    float2 t0 = cadd(v[0], v[4]), t1 = csub(v[0], v[4]);
    float2 t2 = cadd(v[2], v[6]), t3 = csub(v[2], v[6]);
    float2 E0 = cadd(t0, t2), E2 = csub(t0, t2);
    float2 E1 = make_float2(t1.x - t3.y, t1.y + t3.x);   // t1 + i*t3
    float2 E3 = make_float2(t1.x + t3.y, t1.y - t3.x);   // t1 - i*t3
    float2 u0 = cadd(v[1], v[5]), u1 = csub(v[1], v[5]);
    float2 u2 = cadd(v[3], v[7]), u3 = csub(v[3], v[7]);
    float2 O0 = cadd(u0, u2), O2 = csub(u0, u2);
    float2 O1 = make_float2(u1.x - u3.y, u1.y + u3.x);
    float2 O3 = make_float2(u1.x + u3.y, u1.y - u3.x);
    const float C = 0.70710678118654752440f;
    float2 w1 = make_float2(C*(O1.x - O1.y),  C*(O1.x + O1.y));   // W8^1 * O1
    float2 w2 = make_float2(-O2.y, O2.x);                         // i * O2
    float2 w3 = make_float2(-C*(O3.x + O3.y), C*(O3.x - O3.y));   // W8^3 * O3
    v[0] = cadd(E0, O0); v[4] = csub(E0, O0);
    v[1] = cadd(E1, w1); v[5] = csub(E1, w1);
    v[2] = cadd(E2, w2); v[6] = csub(E2, w2);
    v[3] = cadd(E3, w3); v[7] = csub(E3, w3);
}

// Block = 16 waves, wave w computes frame f = u0-1+w fully wave-private
// (registers + its own in-place LDS buffer, ZERO barriers), then one
// __syncthreads and a cross-wave gather with plain coalesced stores.
__global__ __launch_bounds__(1024, 8) void istft_kernel(
    const float* __restrict__ re_g, const float* __restrict__ im_g,
    float* __restrict__ out)
{
    __shared__ float2 Xbuf[16][576];   // per-wave time-domain (phys(511)=574 max)
    __shared__ float  win[1024];       // normalized Hann window

    const int tid  = threadIdx.x;
    const int wave = tid >> 6;
    const int lane = tid & 63;
    const int b    = blockIdx.y;
    const int u0   = blockIdx.x * HOPS_PER_BLOCK;
    const int f    = u0 - 1 + wave;                 // frame this wave computes
    const bool valid = (f >= 0) && (f < FRAMES);

    // window table: win[m] = (0.5 - 0.5 cos(2 pi m/1024)) / 1.5
    win[tid] = (0.5f - 0.5f * cosf((float)tid * (TWO_PI / 1024.0f))) * (2.0f / 3.0f);

    float2* Xb = Xbuf[wave];

    if (valid) {
        const long long off = (long long)(b * FRAMES + f) * BINS;
        const float* re = re_g + off;
        const float* im = im_g + off;

        // per-lane pack twiddle e^{2pi i (l+64j)/1024} via recurrence
        float bs, bc;
        sincosf((float)lane * (TWO_PI / 1024.0f), &bs, &bc);
        const float2 base = make_float2(bc, bs);
        const float2 step = make_float2(0.92387953251128675613f,   // cos(pi/8)
                                        0.38268343236508977173f);  // sin(pi/8)

        // ---- load + Hermitian pack straight into stage-1 registers ----
        // v[j] = Z[l+64j],  Z[k] = (S + i*t*D)/1024,
        // S = X[k]+conj(X[512-k]), D = X[k]-conj(X[512-k]), t = e^{2pi i k/1024}
        float2 v[8];
        float2 tk = base;
        #pragma unroll
        for (int j = 0; j < 8; ++j) {
            int k = lane + 64*j;
            float xar = re[k];
            float xai = (k == 0) ? 0.0f : im[k];         // irfft ignores Im(DC)
            float xcr = re[512 - k];
            float xci = (k == 0) ? 0.0f : im[512 - k];   // Im(Nyquist) ignored
            float Sx = xar + xcr, Sy = xai - xci;
            float Dx = xar - xcr, Dy = xai + xci;
            v[j].x = (Sx - tk.x*Dy - tk.y*Dx) * (1.0f/1024.0f);
            v[j].y = (Sy + tk.x*Dx - tk.y*Dy) * (1.0f/1024.0f);
            tk = cmul(tk, step);
        }

        // ---- 512-pt inverse FFT: 3 x radix-8 Stockham, in-place per wave ----
        // stage 1: v[r]=Z[l+64r] (already in regs) -> Xb[8l+t] * e^{2pi i l t/512}
        bfly8(v);
        {
            float2 w1 = cmul(base, base);              // e^{2pi i l/512}
            float2 twd = make_float2(1.0f, 0.0f);
            int basei = phys(8*lane);                  // == 9l, t contiguous
            #pragma unroll
            for (int t = 0; t < 8; ++t) {
                Xb[basei + t] = cmul(v[t], twd);
                twd = cmul(twd, w1);
            }
        }
        // stage 2: read Xb[l+64r] -> write Xb[q+64p+8t] * e^{2pi i p t/64}
        // (same-wave DS ops are processed in order; lockstep wave -> no barrier)
        {
            #pragma unroll
            for (int r = 0; r < 8; ++r) v[r] = Xb[phys(lane + 64*r)];
            bfly8(v);
            int p = lane >> 3, q = lane & 7;
            float ws, wc; sincosf((float)p * (TWO_PI / 64.0f), &ws, &wc);
            float2 w1 = make_float2(wc, ws);
            float2 twd = make_float2(1.0f, 0.0f);
            #pragma unroll
            for (int t = 0; t < 8; ++t) {
                Xb[phys(q + 64*p + 8*t)] = cmul(v[t], twd);
                twd = cmul(twd, w1);
            }
        }
        // stage 3: read Xb[l+64r] -> write Xb[l+64t], no twiddle
        {
            #pragma unroll
            for (int r = 0; r < 8; ++r) v[r] = Xb[phys(lane + 64*r)];
            bfly8(v);
            #pragma unroll
            for (int t = 0; t < 8; ++t) Xb[phys(lane + 64*t)] = v[t];
        }
    }
    __syncthreads();   // the ONLY barrier: publish frame buffers + win table

    // ---- gather: out[256u+r] = sum_{q=0..3} win[r+256q] * x_{u+2-q}[r+256q] ----
    // x stored interleaved: x[m] = Xbuf[f'-u0+1][phys(m>>1)].{x if m even else y}
    const int nU   = min(HOPS_PER_BLOCK, (OUT_LEN/256) - u0);   // 511 hops total
    const int nOut = nU * 256;
    float* outp = out + (long long)b * OUT_LEN + 256 * u0;
    for (int tl = tid; tl < nOut; tl += 1024) {
        int r  = tl & 255;
        int u  = u0 + (tl >> 8);
        float sum = 0.0f;
        #pragma unroll
        for (int qq = 0; qq < 4; ++qq) {
            int ff = u + 2 - qq;
            if (ff >= 0 && ff < FRAMES) {
                int w  = ff - u0 + 1;              // wave buffer index, 0..15
                int m  = r + 256*qq;
                float2 z = Xbuf[w][phys(m >> 1)];
                float val = (m & 1) ? z.y : z.x;
                sum += val * win[m];
            }
        }
        outp[tl] = sum;
    }
}

extern "C" void kernel_launch(void* const* d_in, const int* in_sizes, int n_in,
                              void* d_out, int out_size, void* d_ws, size_t ws_size,
                              hipStream_t stream) {
    const float* real = (const float*)d_in[0];
    const float* imag = (const float*)d_in[1];
    float* out = (float*)d_out;

    // 511 output hops per row, 13 per block -> 40 blocks per row
    dim3 grid((OUT_LEN/256 + HOPS_PER_BLOCK - 1) / HOPS_PER_BLOCK, BATCH);
    dim3 block(1024);
    istft_kernel<<<grid, block, 0, stream>>>(real, imag, out);
}

// Round 4
// 164.112 us; speedup vs baseline: 2.2401x; 1.0279x over previous
//
#include <hip/hip_runtime.h>

// ISTFT: B=64, FRAMES=512, BINS=513, FFT_LEN=1024, STRIDE=256
// out: (64, 130816) fp32
#define BATCH    64
#define FRAMES   512
#define BINS     513
#define OUT_LEN  130816            // 256*511
#define HOPS_PER_BLOCK 13          // owned output hops; frames needed = 13+3 = 16 waves

__device__ __forceinline__ float2 cadd(float2 a, float2 b){ return make_float2(a.x+b.x, a.y+b.y); }
__device__ __forceinline__ float2 csub(float2 a, float2 b){ return make_float2(a.x-b.x, a.y-b.y); }
__device__ __forceinline__ float2 cmul(float2 a, float2 b){
    return make_float2(a.x*b.x - a.y*b.y, a.x*b.y + a.y*b.x);
}
// e^{2*pi*i*t}, t in REVOLUTIONS, t in [0,1): raw v_sin/v_cos, no range reduction
__device__ __forceinline__ float2 cexp_rev(float t){
    return make_float2(__builtin_amdgcn_cosf(t), __builtin_amdgcn_sinf(t));
}
// LDS pad: +1 float2 every 16. All stage patterns (stride-64 reads, 8l+t writes,
// q+64p+8t writes, gather) land at the uniform 2-way bank-pair = b64 minimum passes.
__device__ __forceinline__ int phys(int i){ return i + (i >> 4); }

// 8-point inverse DFT (positive twiddle sign), in place.
__device__ __forceinline__ void bfly8(float2 v[8]) {
    float2 t0 = cadd(v[0], v[4]), t1 = csub(v[0], v[4]);
    float2 t2 = cadd(v[2], v[6]), t3 = csub(v[2], v[6]);
    float2 E0 = cadd(t0, t2), E2 = csub(t0, t2);
    float2 E1 = make_float2(t1.x - t3.y, t1.y + t3.x);   // t1 + i*t3
    float2 E3 = make_float2(t1.x + t3.y, t1.y - t3.x);   // t1 - i*t3
    float2 u0 = cadd(v[1], v[5]), u1 = csub(v[1], v[5]);
    float2 u2 = cadd(v[3], v[7]), u3 = csub(v[3], v[7]);
    float2 O0 = cadd(u0, u2), O2 = csub(u0, u2);
    float2 O1 = make_float2(u1.x - u3.y, u1.y + u3.x);
    float2 O3 = make_float2(u1.x + u3.y, u1.y - u3.x);
    const float C = 0.70710678118654752440f;
    float2 w1 = make_float2(C*(O1.x - O1.y),  C*(O1.x + O1.y));   // W8^1 * O1
    float2 w2 = make_float2(-O2.y, O2.x);                         // i * O2
    float2 w3 = make_float2(-C*(O3.x + O3.y), C*(O3.x - O3.y));   // W8^3 * O3
    v[0] = cadd(E0, O0); v[4] = csub(E0, O0);
    v[1] = cadd(E1, w1); v[5] = csub(E1, w1);
    v[2] = cadd(E2, w2); v[6] = csub(E2, w2);
    v[3] = cadd(E3, w3); v[7] = csub(E3, w3);
}

// Block = 16 waves, wave w computes frame f = u0-1+w fully wave-private
// (registers + its own in-place LDS buffer, ZERO barriers), then one
// __syncthreads and a cross-wave gather with plain coalesced stores.
__global__ __launch_bounds__(1024, 8) void istft_kernel(
    const float* __restrict__ re_g, const float* __restrict__ im_g,
    float* __restrict__ out)
{
    __shared__ float2 Xbuf[16][544];   // phys(511) = 542 max
    __shared__ float  win[1024];       // hann/1.5/1024 (irfft scale folded in)

    const int tid  = threadIdx.x;
    const int wave = tid >> 6;
    const int lane = tid & 63;
    const int b    = blockIdx.y;
    const int u0   = blockIdx.x * HOPS_PER_BLOCK;
    const int f    = u0 - 1 + wave;                 // frame this wave computes
    const bool valid = (f >= 0) && (f < FRAMES);

    // win[m] = (0.5 - 0.5 cos(2 pi m/1024)) * (2/3) * (1/1024)
    win[tid] = (0.5f - 0.5f * __builtin_amdgcn_cosf((float)tid * (1.0f/1024.0f)))
               * (2.0f / 3.0f / 1024.0f);

    float2* Xb = Xbuf[wave];

    if (valid) {
        const long long off = (long long)(b * FRAMES + f) * BINS;
        const float* re = re_g + off;
        const float* im = im_g + off;

        // ---- load + Hermitian pack straight into stage-1 registers ----
        // v[j] = Z[l+64j] (unscaled), Z[k] = S + i*t*D,
        // S = X[k]+conj(X[512-k]), D = X[k]-conj(X[512-k]), t = e^{2pi i k/1024}
        const float a0 = (float)lane * (1.0f/1024.0f);
        float2 v[8];
        #pragma unroll
        for (int j = 0; j < 8; ++j) {
            int k = lane + 64*j;
            float xar = re[k];
            float xai = (k == 0) ? 0.0f : im[k];         // irfft ignores Im(DC)
            float xcr = re[512 - k];
            float xci = (k == 0) ? 0.0f : im[512 - k];   // Im(Nyquist) ignored
            float Sx = xar + xcr, Sy = xai - xci;
            float Dx = xar - xcr, Dy = xai + xci;
            float2 tk = cexp_rev(a0 + (float)j * (1.0f/16.0f));  // exact dyadic arg
            v[j].x = Sx - tk.x*Dy - tk.y*Dx;
            v[j].y = Sy + tk.x*Dx - tk.y*Dy;
        }

        // ---- 512-pt inverse FFT: 3 x radix-8 Stockham, in-place per wave ----
        // stage 1: v[r]=Z[l+64r] (in regs) -> Xb[8l+t] * e^{2pi i l t/512}
        bfly8(v);
        {
            const float lt = (float)lane * (1.0f/512.0f);
            int basei = phys(8*lane);                  // = 8l+(l>>1); t contiguous
            Xb[basei] = v[0];
            #pragma unroll
            for (int t = 1; t < 8; ++t)
                Xb[basei + t] = cmul(v[t], cexp_rev((float)t * lt));
        }
        // stage 2: read Xb[l+64r] -> write Xb[q+64p+8t] * e^{2pi i p t/64}
        // (same-wave DS ops processed in order; lockstep wave -> no barrier)
        {
            #pragma unroll
            for (int r = 0; r < 8; ++r) v[r] = Xb[phys(lane + 64*r)];
            bfly8(v);
            int p = lane >> 3, q = lane & 7;
            const float pf = (float)p * (1.0f/64.0f);
            Xb[phys(q + 64*p)] = v[0];
            #pragma unroll
            for (int t = 1; t < 8; ++t)
                Xb[phys(q + 64*p + 8*t)] = cmul(v[t], cexp_rev((float)t * pf));
        }
        // stage 3: read Xb[l+64r] -> write Xb[l+64t], no twiddle
        {
            #pragma unroll
            for (int r = 0; r < 8; ++r) v[r] = Xb[phys(lane + 64*r)];
            bfly8(v);
            #pragma unroll
            for (int t = 0; t < 8; ++t) Xb[phys(lane + 64*t)] = v[t];
        }
    }
    __syncthreads();   // the ONLY barrier: publish frame buffers + win table

    // ---- gather: out[256u+r] = sum_{q=0..3} win[r+256q] * x_{u+2-q}[r+256q] ----
    // x stored interleaved: x[m] = Xbuf[f'-u0+1][phys(m>>1)].{x if m even else y}
    const int nU   = min(HOPS_PER_BLOCK, (OUT_LEN/256) - u0);   // 511 hops total
    const int nOut = nU * 256;
    float* outp = out + (long long)b * OUT_LEN + 256 * u0;
    for (int tl = tid; tl < nOut; tl += 1024) {
        int r  = tl & 255;
        int u  = u0 + (tl >> 8);
        float sum = 0.0f;
        #pragma unroll
        for (int qq = 0; qq < 4; ++qq) {
            int ff = u + 2 - qq;
            if (ff >= 0 && ff < FRAMES) {
                int w  = ff - u0 + 1;              // wave buffer index, 0..15
                int m  = r + 256*qq;
                float2 z = Xbuf[w][phys(m >> 1)];
                float val = (m & 1) ? z.y : z.x;
                sum += val * win[m];
            }
        }
        outp[tl] = sum;
    }
}

extern "C" void kernel_launch(void* const* d_in, const int* in_sizes, int n_in,
                              void* d_out, int out_size, void* d_ws, size_t ws_size,
                              hipStream_t stream) {
    const float* real = (const float*)d_in[0];
    const float* imag = (const float*)d_in[1];
    float* out = (float*)d_out;

    // 511 output hops per row, 13 per block -> 40 blocks per row
    dim3 grid((OUT_LEN/256 + HOPS_PER_BLOCK - 1) / HOPS_PER_BLOCK, BATCH);
    dim3 block(1024);
    istft_kernel<<<grid, block, 0, stream>>>(real, imag, out);
}